// Round 3
// baseline (443.233 us; speedup 1.0000x reference)
//
#include <hip/hip_runtime.h>

// Local 3x3 variance (zero-padded, stride 1, divisor 9) over (8,32,512,512) fp32.
// out = boxsum(x^2)/9 - (boxsum(x)/9)^2
//
// Round 3: full-row waves, shfl-only halos, fat coalesced VMEM.
//  - One wave owns a full 512-col x 16-row tile. Lane holds TWO float4s:
//    cols [lane*4, lane*4+3] and [256+lane*4, 256+lane*4+3] -> every load and
//    store instruction is a perfectly coalesced, contiguous 1 KB transaction.
//  - Column halos entirely via __shfl (seam at col 255/256 handled by two
//    broadcast shfls); zero scalar halo loads. Body is branch-free and
//    exec-uniform.
//  - Zero padding = clamped row pointer + 0/1 row mask multiply.
//  - Depth-3 row prefetch (6 outstanding 1 KB loads per wave), 18-iteration
//    loop fully unrolled so the pipeline rotation renames away.
//  - __launch_bounds__(256,4): ~80-90 VGPR fits, 16 waves/CU; in-flight
//    bytes/CU ~ 96 KB >> ~23 KB needed for 6.4 TB/s.

#define IMG_H 512
#define IMG_W 512
#define TH 16   // output rows per wave
#define PF 3    // row prefetch depth

typedef float vfloat4 __attribute__((ext_vector_type(4)));  // for nontemporal store

__global__ __launch_bounds__(256, 4) void var3x3_kernel(const float* __restrict__ x,
                                                        float* __restrict__ out) {
    const int tid   = threadIdx.x;
    const int lane  = tid & 63;
    const int wavei = tid >> 6;         // 0..3
    const int hc    = blockIdx.x;       // 0..7   (64-row chunks)
    const int plane = blockIdx.y;       // 0..255 (b*c)

    const float* __restrict__ px = x   + (size_t)plane * (IMG_H * IMG_W);
    float*       __restrict__ po = out + (size_t)plane * (IMG_H * IMG_W);

    const int c0 = lane * 4;            // left 1KB segment
    const int c1 = 256 + lane * 4;      // right 1KB segment
    const int r0 = hc * 64 + wavei * TH;

    const float inv9 = 1.0f / 9.0f;

    // load input row r0-1+j (clamped) into a pipeline slot
#define LOADROW(V0, V1, M, j) do {                                           \
        const int h_  = r0 - 1 + (j);                                        \
        const int hcl = h_ < 0 ? 0 : (h_ > IMG_H - 1 ? IMG_H - 1 : h_);      \
        const float* p_ = px + (size_t)hcl * IMG_W;                          \
        V0 = *reinterpret_cast<const float4*>(p_ + c0);                      \
        V1 = *reinterpret_cast<const float4*>(p_ + c1);                      \
        M = (h_ >= 0 && h_ < IMG_H) ? 1.0f : 0.0f;                           \
    } while (0)

    // 3-row pipeline
    float4 a0, a1, b0, b1, cc0, cc1;
    float  ma, mb, mc;
    LOADROW(a0, a1, ma, 0);
    LOADROW(b0, b1, mb, 1);
    LOADROW(cc0, cc1, mc, 2);

    // rolling horizontal 3-sums (two column blocks each)
    float4 rsA0 = {0,0,0,0}, rsA1 = {0,0,0,0}, rsB0 = {0,0,0,0}, rsB1 = {0,0,0,0};
    float4 rqA0 = {0,0,0,0}, rqA1 = {0,0,0,0}, rqB0 = {0,0,0,0}, rqB1 = {0,0,0,0};

    // iteration i consumes input row r0-1+i; emits output row r0+i-2 for i>=2
    #pragma unroll
    for (int i = 0; i < TH + 2; ++i) {
        float4 v0 = a0, v1 = a1;
        const float m = ma;

        // rotate pipeline (renamed away by full unroll)
        a0 = b0; a1 = b1; ma = mb;
        b0 = cc0; b1 = cc1; mb = mc;
        if (i + PF < TH + 2) {             // compile-time after unroll
            LOADROW(cc0, cc1, mc, i + PF);
        }

        // zero-padding row mask (halos inherit it since they're shfl'd after)
        v0.x *= m; v0.y *= m; v0.z *= m; v0.w *= m;
        v1.x *= m; v1.y *= m; v1.z *= m; v1.w *= m;

        // column halos, all from registers via shfl
        const float l0s = __shfl_up(v0.w, 1);
        const float l1s = __shfl_up(v1.w, 1);
        const float r0s = __shfl_down(v0.x, 1);
        const float r1s = __shfl_down(v1.x, 1);
        const float seamL = __shfl(v0.w, 63);   // col 255 -> lane 0 of block 1
        const float seamR = __shfl(v1.x, 0);    // col 256 -> lane 63 of block 0
        const float l0 = (lane == 0)  ? 0.f   : l0s;   // col -1 is padding
        const float l1 = (lane == 0)  ? seamL : l1s;
        const float rr0 = (lane == 63) ? seamR : r0s;
        const float r1 = (lane == 63) ? 0.f   : r1s;   // col 512 is padding

        // 3-wide horizontal sums for this row, both column blocks
        float4 rsC0, rqC0, rsC1, rqC1;
        rsC0.x = l0   + v0.x + v0.y;
        rsC0.y = v0.x + v0.y + v0.z;
        rsC0.z = v0.y + v0.z + v0.w;
        rsC0.w = v0.z + v0.w + rr0;
        rsC1.x = l1   + v1.x + v1.y;
        rsC1.y = v1.x + v1.y + v1.z;
        rsC1.z = v1.y + v1.z + v1.w;
        rsC1.w = v1.z + v1.w + r1;
        {
            const float l2 = l0*l0,  a2 = v0.x*v0.x, b2 = v0.y*v0.y;
            const float c2 = v0.z*v0.z, d2 = v0.w*v0.w, r2 = rr0*rr0;
            rqC0.x = l2 + a2 + b2;
            rqC0.y = a2 + b2 + c2;
            rqC0.z = b2 + c2 + d2;
            rqC0.w = c2 + d2 + r2;
        }
        {
            const float l2 = l1*l1,  a2 = v1.x*v1.x, b2 = v1.y*v1.y;
            const float c2 = v1.z*v1.z, d2 = v1.w*v1.w, r2 = r1*r1;
            rqC1.x = l2 + a2 + b2;
            rqC1.y = a2 + b2 + c2;
            rqC1.z = b2 + c2 + d2;
            rqC1.w = c2 + d2 + r2;
        }

        if (i >= 2) {                      // compile-time after unroll
            const int ho = r0 + i - 2;
            float* pr = po + (size_t)ho * IMG_W;
            vfloat4 o;
            { const float s = rsA0.x+rsB0.x+rsC0.x, q = rqA0.x+rqB0.x+rqC0.x, mm = s*inv9; o.x = q*inv9 - mm*mm; }
            { const float s = rsA0.y+rsB0.y+rsC0.y, q = rqA0.y+rqB0.y+rqC0.y, mm = s*inv9; o.y = q*inv9 - mm*mm; }
            { const float s = rsA0.z+rsB0.z+rsC0.z, q = rqA0.z+rqB0.z+rqC0.z, mm = s*inv9; o.z = q*inv9 - mm*mm; }
            { const float s = rsA0.w+rsB0.w+rsC0.w, q = rqA0.w+rqB0.w+rqC0.w, mm = s*inv9; o.w = q*inv9 - mm*mm; }
            __builtin_nontemporal_store(o, reinterpret_cast<vfloat4*>(pr + c0));
            { const float s = rsA1.x+rsB1.x+rsC1.x, q = rqA1.x+rqB1.x+rqC1.x, mm = s*inv9; o.x = q*inv9 - mm*mm; }
            { const float s = rsA1.y+rsB1.y+rsC1.y, q = rqA1.y+rqB1.y+rqC1.y, mm = s*inv9; o.y = q*inv9 - mm*mm; }
            { const float s = rsA1.z+rsB1.z+rsC1.z, q = rqA1.z+rqB1.z+rqC1.z, mm = s*inv9; o.z = q*inv9 - mm*mm; }
            { const float s = rsA1.w+rsB1.w+rsC1.w, q = rqA1.w+rqB1.w+rqC1.w, mm = s*inv9; o.w = q*inv9 - mm*mm; }
            __builtin_nontemporal_store(o, reinterpret_cast<vfloat4*>(pr + c1));
        }
        rsA0 = rsB0; rsB0 = rsC0;  rsA1 = rsB1; rsB1 = rsC1;
        rqA0 = rqB0; rqB0 = rqC0;  rqA1 = rqB1; rqB1 = rqC1;
    }
#undef LOADROW
}

extern "C" void kernel_launch(void* const* d_in, const int* in_sizes, int n_in,
                              void* d_out, int out_size, void* d_ws, size_t ws_size,
                              hipStream_t stream) {
    const float* x = (const float*)d_in[0];
    float* out = (float*)d_out;
    dim3 grid(8, 256);      // 64-row chunks, planes (8*32)
    dim3 block(256);        // 4 independent waves, each a 512x16 tile
    var3x3_kernel<<<grid, block, 0, stream>>>(x, out);
}

// Round 4
// 428.563 us; speedup vs baseline: 1.0342x; 1.0342x over previous
//
#include <hip/hip_runtime.h>

// Local 3x3 variance (zero-padded, stride 1, divisor 9) over (8,32,512,512) fp32.
// out = boxsum(x^2)/9 - (boxsum(x)/9)^2
//
// Round 4: maximum-TLP "fill-kernel-shaped" design. One wave = ONE output row.
//  - 6 independent 1KB-coalesced loads (rows r-1,r,r+1 x two 256-col segments)
//    issued back-to-back; no software pipeline, no rolling state. Latency is
//    hidden by wave count alone: ~50 VGPR -> __launch_bounds__(256,8) ->
//    32 waves/CU (vs 24 for the pipelined variant), 131072 short waves.
//  - Vertical (row) sums first -- pointwise, no halo. Horizontal 3-sum second,
//    on the vertical sums, so the column-halo shfl pass happens once, not per row.
//  - Zero padding: clamped row pointers + 0/1 mask on the outer rows
//    (wave-uniform), lane-edge selects for the column halos.
//  - Input rows are logically read 3x, but adjacent row-waves run near-
//    simultaneously: L1/L2/LLC dedup keeps HBM fetch ~1x (R1 showed FETCH <
//    input size). Stores nontemporal.

#define IMG_H 512
#define IMG_W 512

typedef float vfloat4 __attribute__((ext_vector_type(4)));  // for nontemporal store

__global__ __launch_bounds__(256, 8) void var3x3_kernel(const float* __restrict__ x,
                                                        float* __restrict__ out) {
    const int tid   = threadIdx.x;
    const int lane  = tid & 63;
    const int wavei = tid >> 6;                 // 0..3
    const int r     = blockIdx.x * 4 + wavei;   // output row 0..511
    const int plane = blockIdx.y;               // 0..255 (b*c)

    const float* __restrict__ px = x   + (size_t)plane * (IMG_H * IMG_W);
    float*       __restrict__ po = out + (size_t)plane * (IMG_H * IMG_W);

    const int c0 = lane * 4;            // left 1KB segment
    const int c1 = 256 + lane * 4;      // right 1KB segment

    const int   ru = (r > 0)         ? r - 1 : 0;
    const int   rd = (r < IMG_H - 1) ? r + 1 : IMG_H - 1;
    const float mu = (r > 0)         ? 1.f : 0.f;   // wave-uniform row masks
    const float md = (r < IMG_H - 1) ? 1.f : 0.f;

    const float* pu = px + (size_t)ru * IMG_W;
    const float* pm = px + (size_t)r  * IMG_W;
    const float* pd = px + (size_t)rd * IMG_W;

    // six independent 1KB-coalesced loads, issued back-to-back
    const float4 u0 = *reinterpret_cast<const float4*>(pu + c0);
    const float4 u1 = *reinterpret_cast<const float4*>(pu + c1);
    const float4 m0 = *reinterpret_cast<const float4*>(pm + c0);
    const float4 m1 = *reinterpret_cast<const float4*>(pm + c1);
    const float4 d0 = *reinterpret_cast<const float4*>(pd + c0);
    const float4 d1 = *reinterpret_cast<const float4*>(pd + c1);

    // vertical sums of x and x^2 (zero-pad via mask; mask==mask^2 since 0/1)
    float4 cs0, cq0, cs1, cq1;
#define VERT(CS, CQ, U, M, D, C)                                   \
    { const float vu = mu * U.C, vm = M.C, vd = md * D.C;          \
      CS.C = vu + vm + vd;                                         \
      CQ.C = vu * vu + vm * vm + vd * vd; }
    VERT(cs0, cq0, u0, m0, d0, x) VERT(cs0, cq0, u0, m0, d0, y)
    VERT(cs0, cq0, u0, m0, d0, z) VERT(cs0, cq0, u0, m0, d0, w)
    VERT(cs1, cq1, u1, m1, d1, x) VERT(cs1, cq1, u1, m1, d1, y)
    VERT(cs1, cq1, u1, m1, d1, z) VERT(cs1, cq1, u1, m1, d1, w)
#undef VERT

    // column halos of the vertical sums (one shfl pass for s and q each)
    const float sL0s = __shfl_up(cs0.w, 1);
    const float sL1s = __shfl_up(cs1.w, 1);
    const float sR0s = __shfl_down(cs0.x, 1);
    const float sR1s = __shfl_down(cs1.x, 1);
    const float sSeamL = __shfl(cs0.w, 63);   // col 255 -> lane 0 of seg 1
    const float sSeamR = __shfl(cs1.x, 0);    // col 256 -> lane 63 of seg 0
    const float qL0s = __shfl_up(cq0.w, 1);
    const float qL1s = __shfl_up(cq1.w, 1);
    const float qR0s = __shfl_down(cq0.x, 1);
    const float qR1s = __shfl_down(cq1.x, 1);
    const float qSeamL = __shfl(cq0.w, 63);
    const float qSeamR = __shfl(cq1.x, 0);

    const float sL0 = (lane == 0)  ? 0.f    : sL0s;   // col -1: zero pad
    const float sL1 = (lane == 0)  ? sSeamL : sL1s;
    const float sR0 = (lane == 63) ? sSeamR : sR0s;
    const float sR1 = (lane == 63) ? 0.f    : sR1s;   // col 512: zero pad
    const float qL0 = (lane == 0)  ? 0.f    : qL0s;
    const float qL1 = (lane == 0)  ? qSeamL : qL1s;
    const float qR0 = (lane == 63) ? qSeamR : qR0s;
    const float qR1 = (lane == 63) ? 0.f    : qR1s;

    const float inv9 = 1.0f / 9.0f;
    float* pr = po + (size_t)r * IMG_W;
    vfloat4 o;

    // horizontal 3-sums + variance, segment 0
    { const float s = sL0   + cs0.x + cs0.y, q = qL0   + cq0.x + cq0.y, mm = s * inv9; o.x = q * inv9 - mm * mm; }
    { const float s = cs0.x + cs0.y + cs0.z, q = cq0.x + cq0.y + cq0.z, mm = s * inv9; o.y = q * inv9 - mm * mm; }
    { const float s = cs0.y + cs0.z + cs0.w, q = cq0.y + cq0.z + cq0.w, mm = s * inv9; o.z = q * inv9 - mm * mm; }
    { const float s = cs0.z + cs0.w + sR0,   q = cq0.z + cq0.w + qR0,   mm = s * inv9; o.w = q * inv9 - mm * mm; }
    __builtin_nontemporal_store(o, reinterpret_cast<vfloat4*>(pr + c0));

    // segment 1
    { const float s = sL1   + cs1.x + cs1.y, q = qL1   + cq1.x + cq1.y, mm = s * inv9; o.x = q * inv9 - mm * mm; }
    { const float s = cs1.x + cs1.y + cs1.z, q = cq1.x + cq1.y + cq1.z, mm = s * inv9; o.y = q * inv9 - mm * mm; }
    { const float s = cs1.y + cs1.z + cs1.w, q = cq1.y + cq1.z + cq1.w, mm = s * inv9; o.z = q * inv9 - mm * mm; }
    { const float s = cs1.z + cs1.w + sR1,   q = cq1.z + cq1.w + qR1,   mm = s * inv9; o.w = q * inv9 - mm * mm; }
    __builtin_nontemporal_store(o, reinterpret_cast<vfloat4*>(pr + c1));
}

extern "C" void kernel_launch(void* const* d_in, const int* in_sizes, int n_in,
                              void* d_out, int out_size, void* d_ws, size_t ws_size,
                              hipStream_t stream) {
    const float* x = (const float*)d_in[0];
    float* out = (float*)d_out;
    dim3 grid(128, 256);    // 4-row blocks, planes (8*32)
    dim3 block(256);        // 4 waves, each one full 512-col output row
    var3x3_kernel<<<grid, block, 0, stream>>>(x, out);
}